// Round 7
// baseline (328.924 us; speedup 1.0000x reference)
//
#include <hip/hip_runtime.h>
#include <cmath>

typedef __bf16 bf16;
typedef __bf16 bf16x8 __attribute__((ext_vector_type(8)));
typedef __bf16 bf16x4 __attribute__((ext_vector_type(4)));
typedef __bf16 bf16x2 __attribute__((ext_vector_type(2)));
typedef float floatx4 __attribute__((ext_vector_type(4)));
typedef unsigned int uint;

#define MFMA16(A, B, C) __builtin_amdgcn_mfma_f32_16x16x32_bf16((A), (B), (C), 0, 0, 0)

// async 16B/lane global->LDS (lds dest = wave-uniform base + lane*16)
#define GLDS16(g, l)                                                   \
  __builtin_amdgcn_global_load_lds(                                    \
      (const __attribute__((address_space(1))) void*)(g),              \
      (__attribute__((address_space(3))) void*)(l), 16, 0, 0)

static __device__ __forceinline__ int pack2(float a, float b) {
  bf16x2 t;
  t[0] = (bf16)a;
  t[1] = (bf16)b;
  return __builtin_bit_cast(int, t);
}

// ---------------------------------------------------------------------------
// fused: LN1 (y<1024: row = x*1024+y -> XCD = row/1024, matching the GEMM
// m-stripe so h1's producer and qkv's A-reader share an XCD L2) + fp32->bf16
// weight convert (y>=1024).
// ---------------------------------------------------------------------------
__global__ __launch_bounds__(256) void pre_kernel(
    const float* __restrict__ x, const float* __restrict__ g,
    const float* __restrict__ be, bf16* __restrict__ h1,
    const float* __restrict__ s0, bf16* __restrict__ d0, int n0,
    const float* __restrict__ s1, bf16* __restrict__ d1, int n1,
    const float* __restrict__ s2, bf16* __restrict__ d2, int n2,
    const float* __restrict__ s3, bf16* __restrict__ d3, int n3) {
  int t = threadIdx.x;
  if (blockIdx.y < 1024) {
    int row = blockIdx.x * 1024 + blockIdx.y;  // flat%8 = x = row/1024
    const float* xr = x + (size_t)row * 768;
    float v0 = xr[t], v1 = xr[t + 256], v2 = xr[t + 512];
    float s = v0 + v1 + v2;
    float s2 = v0 * v0 + v1 * v1 + v2 * v2;
#pragma unroll
    for (int o = 1; o < 64; o <<= 1) {
      s += __shfl_xor(s, o, 64);
      s2 += __shfl_xor(s2, o, 64);
    }
    __shared__ float red[8];
    int w = t >> 6, lane = t & 63;
    if (lane == 0) { red[w] = s; red[4 + w] = s2; }
    __syncthreads();
    float ts = red[0] + red[1] + red[2] + red[3];
    float ts2 = red[4] + red[5] + red[6] + red[7];
    float mean = ts * (1.0f / 768.0f);
    float var = ts2 * (1.0f / 768.0f) - mean * mean;
    float rstd = rsqrtf(var + 1e-5f);
    bf16* orow = h1 + (size_t)row * 768;
    orow[t]       = (bf16)((v0 - mean) * rstd * g[t]       + be[t]);
    orow[t + 256] = (bf16)((v1 - mean) * rstd * g[t + 256] + be[t + 256]);
    orow[t + 512] = (bf16)((v2 - mean) * rstd * g[t + 512] + be[t + 512]);
    return;
  }
  int i = ((blockIdx.y - 1024) * 8 + blockIdx.x) * 256 + t;
  const float* s;
  bf16* d;
  if (i < n0) { s = s0 + (size_t)i * 4; d = d0 + (size_t)i * 4; }
  else if ((i -= n0) < n1) { s = s1 + (size_t)i * 4; d = d1 + (size_t)i * 4; }
  else if ((i -= n1) < n2) { s = s2 + (size_t)i * 4; d = d2 + (size_t)i * 4; }
  else if ((i -= n2) < n3) { s = s3 + (size_t)i * 4; d = d3 + (size_t)i * 4; }
  else return;
  bf16x4 v;
  v[0] = (bf16)s[0]; v[1] = (bf16)s[1]; v[2] = (bf16)s[2]; v[3] = (bf16)s[3];
  *(bf16x4*)d = v;
}

// ---------------------------------------------------------------------------
// LayerNorm over C=768, fp32 in -> bf16 out (x1 -> h2). row = x*1024+y so
// XCD = row/1024: same-XCD handoff from proj's x1 stripe and into fc1's
// h2 A-reads.
// ---------------------------------------------------------------------------
__global__ __launch_bounds__(256) void ln_kernel(const float* __restrict__ x,
                                                 const float* __restrict__ g,
                                                 const float* __restrict__ be,
                                                 bf16* __restrict__ out) {
  int row = blockIdx.x * 1024 + blockIdx.y;
  int t = threadIdx.x;
  const float* xr = x + (size_t)row * 768;
  float v0 = xr[t], v1 = xr[t + 256], v2 = xr[t + 512];
  float s = v0 + v1 + v2;
  float s2 = v0 * v0 + v1 * v1 + v2 * v2;
#pragma unroll
  for (int o = 1; o < 64; o <<= 1) {
    s += __shfl_xor(s, o, 64);
    s2 += __shfl_xor(s2, o, 64);
  }
  __shared__ float red[8];
  int w = t >> 6, lane = t & 63;
  if (lane == 0) { red[w] = s; red[4 + w] = s2; }
  __syncthreads();
  float ts = red[0] + red[1] + red[2] + red[3];
  float ts2 = red[4] + red[5] + red[6] + red[7];
  float mean = ts * (1.0f / 768.0f);
  float var = ts2 * (1.0f / 768.0f) - mean * mean;
  float rstd = rsqrtf(var + 1e-5f);
  bf16* orow = out + (size_t)row * 768;
  orow[t]       = (bf16)((v0 - mean) * rstd * g[t]       + be[t]);
  orow[t + 256] = (bf16)((v1 - mean) * rstd * g[t + 256] + be[t + 256]);
  orow[t + 512] = (bf16)((v2 - mean) * rstd * g[t + 512] + be[t + 512]);
}

// ---------------------------------------------------------------------------
// GEMM: C[m,n] = sum_k A[m,k]*B[n,k] (+bias)  (A:[M,K] bf16, B:[N,K] bf16)
// 128 x (32*NJ) tile, 4 waves, templated BK (64 or 128), global_load_lds
// width=16 into XOR-granule-swizzled rows. 2-barrier K-loop (measured best
// vs dbuf R1 / counted-vmcnt R3). BK=128 for NJ=2 (48 KB, 3 blocks/CU).
// XCD stripe: fid&7 = m-region -> XCD e owns rows [e*1024,(e+1)*1024) for
// both reads (A) and writes (C) -- all activation handoffs same-XCD.
// EP_RES_F32: out = acc + bias + resid (f32) -- used with NJ=2 for N=768.
// ---------------------------------------------------------------------------
constexpr int EP_BF16 = 0;
constexpr int EP_RES_F32 = 1;
constexpr int EP_GELU_BF16 = 2;

template <int EP, int NJ, int BK>
__global__ __launch_bounds__(256, 3) void gemm_bt(
    const bf16* __restrict__ A, const bf16* __restrict__ Bw,
    const float* __restrict__ bias, const float* __restrict__ resid,
    void* __restrict__ outp, int M, int N, int K) {
  constexpr int GR = BK / 8;               // granules per row
  constexpr int RC = 64 / GR;              // rows per 1024B DMA chunk
  constexpr int ACH = 128 / RC / 4;        // A chunks per wave
  constexpr int BCH = (32 * NJ) / RC / 4;  // B chunks per wave
  constexpr int NKS = BK / 32;             // 32-deep MFMA steps per K-step
  __shared__ alignas(16) bf16 Asl[128 * BK];
  __shared__ alignas(16) bf16 Bsl[NJ * 32 * BK];
  int tid = threadIdx.x;
  int lane = tid & 63, w = tid >> 6;
  int wm = w >> 1, wn = w & 1;
  int q16 = lane & 15, quad = lane >> 4;
  int fid = blockIdx.x + gridDim.x * blockIdx.y;
  int nb = gridDim.x;
  int s = fid >> 3;
  int m0 = ((fid & 7) * (gridDim.y >> 3) + s / nb) * 128;
  int n0 = (s % nb) * (NJ * 32);

  floatx4 acc[4][NJ];
#pragma unroll
  for (int i = 0; i < 4; i++)
#pragma unroll
    for (int j = 0; j < NJ; j++) acc[i][j] = (floatx4){0.f, 0.f, 0.f, 0.f};

  // staging: lane L of chunk c -> row c*RC + L/GR, slot L&(GR-1); slot s of
  // row r must hold global k-granule s ^ (r&(GR-1))
  int rIn = lane / GR;
  int sl = lane & (GR - 1);
  const bf16* ag[ACH];
  const bf16* bg[BCH];
#pragma unroll
  for (int q = 0; q < ACH; q++) {
    int row = (w * ACH + q) * RC + rIn;
    ag[q] = A + (size_t)(m0 + row) * K + (size_t)(sl ^ (row & (GR - 1))) * 8;
  }
#pragma unroll
  for (int q = 0; q < BCH; q++) {
    int row = (w * BCH + q) * RC + rIn;
    bg[q] = Bw + (size_t)(n0 + row) * K + (size_t)(sl ^ (row & (GR - 1))) * 8;
  }
  bf16* la = &Asl[w * ACH * 512];
  bf16* lb = &Bsl[w * BCH * 512];

  // frag read offsets: row*BK + ((ks*4+quad) ^ (row&(GR-1)))*8; frag row
  // & (GR-1) always reduces to q16&(GR-1) (other terms are 0 mod GR)
  int swz = q16 & (GR - 1);
  int offA[NKS][4], offB[NKS][NJ];
#pragma unroll
  for (int ks = 0; ks < NKS; ks++) {
#pragma unroll
    for (int i = 0; i < 4; i++)
      offA[ks][i] = (wm * 64 + i * 16 + q16) * BK + ((ks * 4 + quad) ^ swz) * 8;
#pragma unroll
    for (int j = 0; j < NJ; j++)
      offB[ks][j] = (wn * 16 * NJ + j * 16 + q16) * BK + ((ks * 4 + quad) ^ swz) * 8;
  }

  for (int k0 = 0; k0 < K; k0 += BK) {
    __syncthreads();
#pragma unroll
    for (int q = 0; q < ACH; q++) {
      GLDS16(ag[q], la + q * 512);
      ag[q] += BK;
    }
#pragma unroll
    for (int q = 0; q < BCH; q++) {
      GLDS16(bg[q], lb + q * 512);
      bg[q] += BK;
    }
    __syncthreads();
#pragma unroll
    for (int ks = 0; ks < NKS; ks++) {
      bf16x8 af[4], bfr[NJ];
#pragma unroll
      for (int i = 0; i < 4; i++) af[i] = *(const bf16x8*)&Asl[offA[ks][i]];
#pragma unroll
      for (int j = 0; j < NJ; j++) bfr[j] = *(const bf16x8*)&Bsl[offB[ks][j]];
#pragma unroll
      for (int i = 0; i < 4; i++)
#pragma unroll
        for (int j = 0; j < NJ; j++) acc[i][j] = MFMA16(af[i], bfr[j], acc[i][j]);
    }
  }

  // epilogue: C/D layout col = lane&15, row = quad*4 + reg  [m89-verified]
#pragma unroll
  for (int i = 0; i < 4; i++) {
#pragma unroll
    for (int j = 0; j < NJ; j++) {
#pragma unroll
      for (int r = 0; r < 4; r++) {
        int m = m0 + wm * 64 + i * 16 + quad * 4 + r;
        int n = n0 + wn * 16 * NJ + j * 16 + q16;
        size_t idx = (size_t)m * N + n;
        float v = acc[i][j][r] + bias[n];
        if constexpr (EP == EP_BF16) {
          ((bf16*)outp)[idx] = (bf16)v;
        } else if constexpr (EP == EP_RES_F32) {
          ((float*)outp)[idx] = v + resid[idx];
        } else {
          // gelu(v) = v * sigmoid(1.59577(v + 0.044715 v^3)); exp2 form
          float u = v * (2.3022083f + 0.1029443f * v * v);
          float e = __builtin_amdgcn_exp2f(-u);
          float gv = v * __builtin_amdgcn_rcpf(1.0f + e);
          ((bf16*)outp)[idx] = (bf16)gv;
        }
      }
    }
  }
}

// ---------------------------------------------------------------------------
// Flash attention, bf16 MFMA. qkv: [B,N,3,12,64] bf16 -> out [B,N,768] bf16.
// R7: grid dim3(8,96), b = blockIdx.x -> flat%8 = b: attn batch b runs on
// XCD b, the SAME XCD whose L2 holds batch b's qkv rows dirty (qkv GEMM
// stripes m-rows [b*1024,(b+1)*1024) to XCD b) and the XCD proj will read
// ob rows b*1024.. from. Kills the cross-XCD dirty-line handoff that made
// attn dispatch-0 run 155us @ 2.5% occupancy in R6. 96 blocks per batch =
// exactly one XCD's capacity (32 CU x 3 blocks).
// KVBLK=64, 4-wave blocks, in-reg P via swapped QK^T, dbuf K/V LDS, single
// barrier per tile, no-max softmax. V staged reg->4x4 transpose->b64 writes.
// ---------------------------------------------------------------------------
__global__ __launch_bounds__(256, 3) void attn_kernel(const bf16* __restrict__ qkv,
                                                      bf16* __restrict__ o) {
  __shared__ alignas(16) bf16 Kl[2][64 * 64];  // [buf][key][d] swizzled, 16KB
  __shared__ alignas(16) bf16 Vt[2][64 * 72];  // [buf][d][key] swizzled, 18KB
  int tid = threadIdx.x;
  int lane = tid & 63, w = tid >> 6;  // w in 0..3
  int q16 = lane & 15, quad = lane >> 4;
  int b = blockIdx.x;                      // XCD = b
  int h = blockIdx.y % 12;
  int qbase = (blockIdx.y / 12) * 128 + w * 32;
  const int KS = 64 * 2304;

  // Q fragments (B-operand layout n=q16, k=quad*8+j), 2 q-tiles x 2 d-chunks
  bf16x8 qf[2][2];
#pragma unroll
  for (int qt = 0; qt < 2; qt++)
#pragma unroll
    for (int c = 0; c < 2; c++)
      qf[qt][c] = *(const bf16x8*)(qkv +
          (size_t)(b * 1024 + qbase + qt * 16 + q16) * 2304 + h * 64 +
          c * 32 + quad * 8);

  // K DMA: wave w stages keys w*16..w*16+15 (two 8-key chunks); lane fetches
  // the 16B chunk that lands (lane-contiguous DMA) at swizzled granule
  // key*8 + (c ^ (key&7))
  int krow = lane >> 3;
  int kchunk = (lane & 7) ^ krow;
  const bf16* kg0 = qkv + (size_t)(b * 1024 + w * 16 + krow) * 2304 + 768 +
                    h * 64 + kchunk * 8;
  const bf16* kg1 = kg0 + 8 * 2304;
  bf16* kdA[2] = {&Kl[0][w * 1024], &Kl[1][w * 1024]};

  // V staging: thread (kg = tid>>4, dg = tid&15): global b64 loads of
  // V[4kg+i][4dg..4dg+3], in-reg 4x4 transpose, 4x ds_write_b64 into the
  // swizzled V^T: elem (d,key) at granule (d*9 + (key>>3)) ^ ((d>>3)&7),
  // sub-elem key&7. Keys 4kg..4kg+3 are granule-half-aligned -> one b64.
  int kg = tid >> 4;
  int dg = tid & 15;
  const bf16* vgp = qkv + (size_t)(b * 1024 + 4 * kg) * 2304 + 1536 + h * 64 +
                    4 * dg;
  int vw[4];
#pragma unroll
  for (int j = 0; j < 4; j++) {
    int d = 4 * dg + j;
    vw[j] = (((d * 9 + (kg >> 1)) ^ ((d >> 3) & 7)) * 8) + (kg & 1) * 4;
  }
  uint2 vr[4];

  // loop-invariant LDS read offsets
  int koff[4][2];
#pragma unroll
  for (int nc = 0; nc < 4; nc++)
#pragma unroll
    for (int ck = 0; ck < 2; ck++) {
      int key = nc * 16 + q16;
      koff[nc][ck] = (key * 8 + ((ck * 4 + quad) ^ (key & 7))) * 8;
    }
  int voff[2][4];
#pragma unroll
  for (int c = 0; c < 2; c++)
#pragma unroll
    for (int dc = 0; dc < 4; dc++) {
      int d = dc * 16 + q16;
      voff[c][dc] = ((d * 9 + (c * 4 + quad)) ^ ((d >> 3) & 7)) * 8;
    }

  int srcLo = q16 + ((quad & 1) << 5);
  int srcHi = srcLo + 16;
  bool loH = quad < 2;

  float lsum[2] = {0.f, 0.f};
  floatx4 oacc[2][4];
#pragma unroll
  for (int qt = 0; qt < 2; qt++)
#pragma unroll
    for (int dc = 0; dc < 4; dc++) oacc[qt][dc] = (floatx4){0.f, 0.f, 0.f, 0.f};

#define VLOAD()                                                        \
  do {                                                                 \
    _Pragma("unroll") for (int i = 0; i < 4; i++)                      \
        vr[i] = *(const uint2*)(vgp + i * 2304);                       \
    vgp += KS;                                                         \
  } while (0)

#define VWRITE(buf)                                                    \
  do {                                                                 \
    uint lo0 = vr[0].x, lo1 = vr[1].x, lo2 = vr[2].x, lo3 = vr[3].x;   \
    uint hi0 = vr[0].y, hi1 = vr[1].y, hi2 = vr[2].y, hi3 = vr[3].y;   \
    uint2 c0, c1, c2, c3;                                              \
    c0.x = (lo0 & 0xFFFFu) | (lo1 << 16);                              \
    c0.y = (lo2 & 0xFFFFu) | (lo3 << 16);                              \
    c1.x = (lo0 >> 16) | (lo1 & 0xFFFF0000u);                          \
    c1.y = (lo2 >> 16) | (lo3 & 0xFFFF0000u);                          \
    c2.x = (hi0 & 0xFFFFu) | (hi1 << 16);                              \
    c2.y = (hi2 & 0xFFFFu) | (hi3 << 16);                              \
    c3.x = (hi0 >> 16) | (hi1 & 0xFFFF0000u);                          \
    c3.y = (hi2 >> 16) | (hi3 & 0xFFFF0000u);                          \
    *(uint2*)&Vt[buf][vw[0]] = c0;                                     \
    *(uint2*)&Vt[buf][vw[1]] = c1;                                     \
    *(uint2*)&Vt[buf][vw[2]] = c2;                                     \
    *(uint2*)&Vt[buf][vw[3]] = c3;                                     \
  } while (0)

  // prologue: stage tile 0 (K-DMA + V write), prefetch V of tile 1 into regs
  GLDS16(kg0, kdA[0]);
  GLDS16(kg1, kdA[0] + 512);
  kg0 += KS; kg1 += KS;
  VLOAD();
  VWRITE(0);
  VLOAD();

  for (int kt = 0; kt < 16; kt++) {
    int cur = kt & 1, nxt = cur ^ 1;
    __syncthreads();  // buf[cur] staged & visible; buf[nxt] free for reuse
    if (kt < 15) {
      GLDS16(kg0, kdA[nxt]);  // in flight during compute below
      GLDS16(kg1, kdA[nxt] + 512);
      kg0 += KS; kg1 += KS;
      VWRITE(nxt);
      if (kt < 14) VLOAD();  // prefetch V of tile kt+2
    }

    // QK^T (swapped): z[qt][nc][r] = S[key = nc*16 + quad*4 + r][q]
    floatx4 z[2][4];
#pragma unroll
    for (int nc = 0; nc < 4; nc++) {
      bf16x8 k0 = *(const bf16x8*)&Kl[cur][koff[nc][0]];
      bf16x8 k1 = *(const bf16x8*)&Kl[cur][koff[nc][1]];
#pragma unroll
      for (int qt = 0; qt < 2; qt++) {
        floatx4 t = (floatx4){0.f, 0.f, 0.f, 0.f};
        t = MFMA16(k0, qf[qt][0], t);
        t = MFMA16(k1, qf[qt][1], t);
        z[qt][nc] = t;
      }
    }

    bf16x8 vf[2][4];
#pragma unroll
    for (int c = 0; c < 2; c++)
#pragma unroll
      for (int dc = 0; dc < 4; dc++)
        vf[c][dc] = *(const bf16x8*)&Vt[cur][voff[c][dc]];

#pragma unroll
    for (int qt = 0; qt < 2; qt++) {
      float e_[4][4];
#pragma unroll
      for (int nc = 0; nc < 4; nc++)
#pragma unroll
        for (int r = 0; r < 4; r++) {
          e_[nc][r] = __builtin_amdgcn_exp2f(z[qt][nc][r] * 0.18033688011f);
          lsum[qt] += e_[nc][r];
        }
      int P[4][2];
#pragma unroll
      for (int nc = 0; nc < 4; nc++) {
        P[nc][0] = pack2(e_[nc][0], e_[nc][1]);
        P[nc][1] = pack2(e_[nc][2], e_[nc][3]);
      }
      union { int i[4]; bf16x8 v; } pu[2];
#pragma unroll
      for (int c = 0; c < 2; c++) {
        int a0 = __shfl(P[2 * c][0], srcLo, 64), b0 = __shfl(P[2 * c + 1][0], srcLo, 64);
        int a1 = __shfl(P[2 * c][1], srcLo, 64), b1 = __shfl(P[2 * c + 1][1], srcLo, 64);
        int a2 = __shfl(P[2 * c][0], srcHi, 64), b2 = __shfl(P[2 * c + 1][0], srcHi, 64);
        int a3 = __shfl(P[2 * c][1], srcHi, 64), b3 = __shfl(P[2 * c + 1][1], srcHi, 64);
        pu[c].i[0] = loH ? a0 : b0;
        pu[c].i[1] = loH ? a1 : b1;
        pu[c].i[2] = loH ? a2 : b2;
        pu[c].i[3] = loH ? a3 : b3;
      }
#pragma unroll
      for (int dc = 0; dc < 4; dc++) {
        oacc[qt][dc] = MFMA16(pu[0].v, vf[0][dc], oacc[qt][dc]);
        oacc[qt][dc] = MFMA16(pu[1].v, vf[1][dc], oacc[qt][dc]);
      }
    }
  }

  // final: l(q16) = sum over the 4 quads (disjoint key sets), broadcast to
  // output rows q = quad*4 + r via shfl, divide, store
#pragma unroll
  for (int qt = 0; qt < 2; qt++) {
    float s = lsum[qt];
    s += __shfl_xor(s, 16, 64);
    s += __shfl_xor(s, 32, 64);
    float inv = 1.0f / s;
    bf16* op = o + (size_t)(b * 1024 + qbase + qt * 16) * 768 + h * 64;
#pragma unroll
    for (int r = 0; r < 4; r++) {
      float invr = __shfl(inv, quad * 4 + r, 64);
#pragma unroll
      for (int dc = 0; dc < 4; dc++)
        op[(size_t)(quad * 4 + r) * 768 + dc * 16 + q16] =
            (bf16)(oacc[qt][dc][r] * invr);
    }
  }
#undef VLOAD
#undef VWRITE
}

// ---------------------------------------------------------------------------
extern "C" void kernel_launch(void* const* d_in, const int* in_sizes, int n_in,
                              void* d_out, int out_size, void* d_ws, size_t ws_size,
                              hipStream_t stream) {
  (void)in_sizes; (void)n_in; (void)out_size; (void)ws_size;
  const float* x      = (const float*)d_in[0];
  const float* ln1_w  = (const float*)d_in[1];
  const float* ln1_b  = (const float*)d_in[2];
  const float* qkv_w  = (const float*)d_in[3];
  const float* qkv_b  = (const float*)d_in[4];
  const float* proj_w = (const float*)d_in[5];
  const float* proj_b = (const float*)d_in[6];
  const float* ln2_w  = (const float*)d_in[7];
  const float* ln2_b  = (const float*)d_in[8];
  const float* fc1_w  = (const float*)d_in[9];
  const float* fc1_b  = (const float*)d_in[10];
  const float* fc2_w  = (const float*)d_in[11];
  const float* fc2_b  = (const float*)d_in[12];

  char* ws = (char*)d_ws;
  size_t off = 0;
  auto alloc = [&](size_t bytes) {
    void* p = ws + off;
    off += (bytes + 255) & ~(size_t)255;
    return p;
  };
  bf16* wq  = (bf16*)alloc((size_t)2304 * 768 * 2);
  bf16* wp  = (bf16*)alloc((size_t)768 * 768 * 2);
  bf16* wf1 = (bf16*)alloc((size_t)3072 * 768 * 2);
  bf16* wf2 = (bf16*)alloc((size_t)768 * 3072 * 2);
  bf16* slotA = (bf16*)alloc((size_t)8192 * 768 * 2);   // h1 / ob / h2
  bf16* slotB = (bf16*)alloc((size_t)8192 * 3072 * 2);  // qkv / fc1-out
  float* x1 = (float*)alloc((size_t)8192 * 768 * 4);

  bf16* h1 = slotA;
  bf16* qkvb = slotB;
  bf16* ob = slotA;
  bf16* h2 = slotA;
  bf16* hm = slotB;

  pre_kernel<<<dim3(8, 1024 + 864), 256, 0, stream>>>(
      x, ln1_w, ln1_b, h1,
      qkv_w, wq, 2304 * 768 / 4, proj_w, wp, 768 * 768 / 4,
      fc1_w, wf1, 3072 * 768 / 4, fc2_w, wf2, 768 * 3072 / 4);

  gemm_bt<EP_BF16, 4, 64><<<dim3(18, 64), 256, 0, stream>>>(
      h1, wq, qkv_b, nullptr, qkvb, 8192, 2304, 768);
  attn_kernel<<<dim3(8, 96), 256, 0, stream>>>(qkvb, ob);
  gemm_bt<EP_RES_F32, 2, 128><<<dim3(12, 64), 256, 0, stream>>>(
      ob, wp, proj_b, x, x1, 8192, 768, 768);
  ln_kernel<<<dim3(8, 1024), 256, 0, stream>>>(x1, ln2_w, ln2_b, h2);
  gemm_bt<EP_GELU_BF16, 4, 64><<<dim3(24, 64), 256, 0, stream>>>(
      h2, wf1, fc1_b, nullptr, hm, 8192, 3072, 768);
  gemm_bt<EP_RES_F32, 2, 128><<<dim3(12, 64), 256, 0, stream>>>(
      hm, wf2, fc2_b, x1, (float*)d_out, 8192, 768, 3072);
}

// Round 8
// 325.543 us; speedup vs baseline: 1.0104x; 1.0104x over previous
//
#include <hip/hip_runtime.h>
#include <cmath>

typedef __bf16 bf16;
typedef __bf16 bf16x8 __attribute__((ext_vector_type(8)));
typedef __bf16 bf16x4 __attribute__((ext_vector_type(4)));
typedef __bf16 bf16x2 __attribute__((ext_vector_type(2)));
typedef float floatx4 __attribute__((ext_vector_type(4)));
typedef unsigned int uint;

#define MFMA16(A, B, C) __builtin_amdgcn_mfma_f32_16x16x32_bf16((A), (B), (C), 0, 0, 0)

// async 16B/lane global->LDS (lds dest = wave-uniform base + lane*16)
#define GLDS16(g, l)                                                   \
  __builtin_amdgcn_global_load_lds(                                    \
      (const __attribute__((address_space(1))) void*)(g),              \
      (__attribute__((address_space(3))) void*)(l), 16, 0, 0)

static __device__ __forceinline__ int pack2(float a, float b) {
  bf16x2 t;
  t[0] = (bf16)a;
  t[1] = (bf16)b;
  return __builtin_bit_cast(int, t);
}

// ---------------------------------------------------------------------------
// fused: LN1 (y<1024: row = x*1024+y -> XCD = row/1024, matching the GEMM
// m-stripe so h1's producer and qkv's A-reader share an XCD L2) + fp32->bf16
// weight convert (y>=1024).
// ---------------------------------------------------------------------------
__global__ __launch_bounds__(256) void pre_kernel(
    const float* __restrict__ x, const float* __restrict__ g,
    const float* __restrict__ be, bf16* __restrict__ h1,
    const float* __restrict__ s0, bf16* __restrict__ d0, int n0,
    const float* __restrict__ s1, bf16* __restrict__ d1, int n1,
    const float* __restrict__ s2, bf16* __restrict__ d2, int n2,
    const float* __restrict__ s3, bf16* __restrict__ d3, int n3) {
  int t = threadIdx.x;
  if (blockIdx.y < 1024) {
    int row = blockIdx.x * 1024 + blockIdx.y;  // flat%8 = x = row/1024
    const float* xr = x + (size_t)row * 768;
    float v0 = xr[t], v1 = xr[t + 256], v2 = xr[t + 512];
    float s = v0 + v1 + v2;
    float s2 = v0 * v0 + v1 * v1 + v2 * v2;
#pragma unroll
    for (int o = 1; o < 64; o <<= 1) {
      s += __shfl_xor(s, o, 64);
      s2 += __shfl_xor(s2, o, 64);
    }
    __shared__ float red[8];
    int w = t >> 6, lane = t & 63;
    if (lane == 0) { red[w] = s; red[4 + w] = s2; }
    __syncthreads();
    float ts = red[0] + red[1] + red[2] + red[3];
    float ts2 = red[4] + red[5] + red[6] + red[7];
    float mean = ts * (1.0f / 768.0f);
    float var = ts2 * (1.0f / 768.0f) - mean * mean;
    float rstd = rsqrtf(var + 1e-5f);
    bf16* orow = h1 + (size_t)row * 768;
    orow[t]       = (bf16)((v0 - mean) * rstd * g[t]       + be[t]);
    orow[t + 256] = (bf16)((v1 - mean) * rstd * g[t + 256] + be[t + 256]);
    orow[t + 512] = (bf16)((v2 - mean) * rstd * g[t + 512] + be[t + 512]);
    return;
  }
  int i = ((blockIdx.y - 1024) * 8 + blockIdx.x) * 256 + t;
  const float* s;
  bf16* d;
  if (i < n0) { s = s0 + (size_t)i * 4; d = d0 + (size_t)i * 4; }
  else if ((i -= n0) < n1) { s = s1 + (size_t)i * 4; d = d1 + (size_t)i * 4; }
  else if ((i -= n1) < n2) { s = s2 + (size_t)i * 4; d = d2 + (size_t)i * 4; }
  else if ((i -= n2) < n3) { s = s3 + (size_t)i * 4; d = d3 + (size_t)i * 4; }
  else return;
  bf16x4 v;
  v[0] = (bf16)s[0]; v[1] = (bf16)s[1]; v[2] = (bf16)s[2]; v[3] = (bf16)s[3];
  *(bf16x4*)d = v;
}

// ---------------------------------------------------------------------------
// LayerNorm over C=768, fp32 in -> bf16 out (x1 -> h2). row = x*1024+y so
// XCD = row/1024: same-XCD handoff from proj's x1 stripe and into fc1's
// h2 A-reads.
// ---------------------------------------------------------------------------
__global__ __launch_bounds__(256) void ln_kernel(const float* __restrict__ x,
                                                 const float* __restrict__ g,
                                                 const float* __restrict__ be,
                                                 bf16* __restrict__ out) {
  int row = blockIdx.x * 1024 + blockIdx.y;
  int t = threadIdx.x;
  const float* xr = x + (size_t)row * 768;
  float v0 = xr[t], v1 = xr[t + 256], v2 = xr[t + 512];
  float s = v0 + v1 + v2;
  float s2 = v0 * v0 + v1 * v1 + v2 * v2;
#pragma unroll
  for (int o = 1; o < 64; o <<= 1) {
    s += __shfl_xor(s, o, 64);
    s2 += __shfl_xor(s2, o, 64);
  }
  __shared__ float red[8];
  int w = t >> 6, lane = t & 63;
  if (lane == 0) { red[w] = s; red[4 + w] = s2; }
  __syncthreads();
  float ts = red[0] + red[1] + red[2] + red[3];
  float ts2 = red[4] + red[5] + red[6] + red[7];
  float mean = ts * (1.0f / 768.0f);
  float var = ts2 * (1.0f / 768.0f) - mean * mean;
  float rstd = rsqrtf(var + 1e-5f);
  bf16* orow = out + (size_t)row * 768;
  orow[t]       = (bf16)((v0 - mean) * rstd * g[t]       + be[t]);
  orow[t + 256] = (bf16)((v1 - mean) * rstd * g[t + 256] + be[t + 256]);
  orow[t + 512] = (bf16)((v2 - mean) * rstd * g[t + 512] + be[t + 512]);
}

// ---------------------------------------------------------------------------
// GEMM: C[m,n] = sum_k A[m,k]*B[n,k] (+bias)  (A:[M,K] bf16, B:[N,K] bf16)
// 128 x (32*NJ) tile, 4 waves, templated BK (64 or 128), global_load_lds
// width=16 into XOR-granule-swizzled rows. 2-barrier K-loop (measured best
// vs dbuf R1 / counted-vmcnt R3). BK=128 for NJ=2 (48 KB, 3 blocks/CU).
// R8: NJ=6 for qkv (grid 768 = EXACTLY 3 blocks/CU, no ragged tail; was
// 1152 = 4.5/CU) and fc1 (grid 1024 = exactly 4/CU). NJ=6 also lifts MFMA
// density: 24 MFMA per 10 ds_read_b128 per ks (vs 16/8). LDS 40KB -> still
// 3 blocks/CU. acc 96 AGPR + ~70 VGPR fits 3 waves/SIMD (512/3=170).
// XCD stripe: fid&7 = m-region -> XCD e owns rows [e*1024,(e+1)*1024).
// EP_RES_F32: out = acc + bias + resid (f32) -- used with NJ=2 for N=768.
// ---------------------------------------------------------------------------
constexpr int EP_BF16 = 0;
constexpr int EP_RES_F32 = 1;
constexpr int EP_GELU_BF16 = 2;

template <int EP, int NJ, int BK>
__global__ __launch_bounds__(256, 3) void gemm_bt(
    const bf16* __restrict__ A, const bf16* __restrict__ Bw,
    const float* __restrict__ bias, const float* __restrict__ resid,
    void* __restrict__ outp, int M, int N, int K) {
  constexpr int GR = BK / 8;               // granules per row
  constexpr int RC = 64 / GR;              // rows per 1024B DMA chunk
  constexpr int ACH = 128 / RC / 4;        // A chunks per wave
  constexpr int BCH = (32 * NJ) / RC / 4;  // B chunks per wave
  constexpr int NKS = BK / 32;             // 32-deep MFMA steps per K-step
  __shared__ alignas(16) bf16 Asl[128 * BK];
  __shared__ alignas(16) bf16 Bsl[NJ * 32 * BK];
  int tid = threadIdx.x;
  int lane = tid & 63, w = tid >> 6;
  int wm = w >> 1, wn = w & 1;
  int q16 = lane & 15, quad = lane >> 4;
  int fid = blockIdx.x + gridDim.x * blockIdx.y;
  int nb = gridDim.x;
  int s = fid >> 3;
  int m0 = ((fid & 7) * (gridDim.y >> 3) + s / nb) * 128;
  int n0 = (s % nb) * (NJ * 32);

  floatx4 acc[4][NJ];
#pragma unroll
  for (int i = 0; i < 4; i++)
#pragma unroll
    for (int j = 0; j < NJ; j++) acc[i][j] = (floatx4){0.f, 0.f, 0.f, 0.f};

  // staging: lane L of chunk c -> row c*RC + L/GR, slot L&(GR-1); slot s of
  // row r must hold global k-granule s ^ (r&(GR-1))
  int rIn = lane / GR;
  int sl = lane & (GR - 1);
  const bf16* ag[ACH];
  const bf16* bg[BCH];
#pragma unroll
  for (int q = 0; q < ACH; q++) {
    int row = (w * ACH + q) * RC + rIn;
    ag[q] = A + (size_t)(m0 + row) * K + (size_t)(sl ^ (row & (GR - 1))) * 8;
  }
#pragma unroll
  for (int q = 0; q < BCH; q++) {
    int row = (w * BCH + q) * RC + rIn;
    bg[q] = Bw + (size_t)(n0 + row) * K + (size_t)(sl ^ (row & (GR - 1))) * 8;
  }
  bf16* la = &Asl[w * ACH * 512];
  bf16* lb = &Bsl[w * BCH * 512];

  // frag read offsets: row*BK + ((ks*4+quad) ^ (row&(GR-1)))*8; frag row
  // & (GR-1) always reduces to q16&(GR-1) (other terms are 0 mod GR)
  int swz = q16 & (GR - 1);
  int offA[NKS][4], offB[NKS][NJ];
#pragma unroll
  for (int ks = 0; ks < NKS; ks++) {
#pragma unroll
    for (int i = 0; i < 4; i++)
      offA[ks][i] = (wm * 64 + i * 16 + q16) * BK + ((ks * 4 + quad) ^ swz) * 8;
#pragma unroll
    for (int j = 0; j < NJ; j++)
      offB[ks][j] = (wn * 16 * NJ + j * 16 + q16) * BK + ((ks * 4 + quad) ^ swz) * 8;
  }

  for (int k0 = 0; k0 < K; k0 += BK) {
    __syncthreads();
#pragma unroll
    for (int q = 0; q < ACH; q++) {
      GLDS16(ag[q], la + q * 512);
      ag[q] += BK;
    }
#pragma unroll
    for (int q = 0; q < BCH; q++) {
      GLDS16(bg[q], lb + q * 512);
      bg[q] += BK;
    }
    __syncthreads();
#pragma unroll
    for (int ks = 0; ks < NKS; ks++) {
      bf16x8 af[4], bfr[NJ];
#pragma unroll
      for (int i = 0; i < 4; i++) af[i] = *(const bf16x8*)&Asl[offA[ks][i]];
#pragma unroll
      for (int j = 0; j < NJ; j++) bfr[j] = *(const bf16x8*)&Bsl[offB[ks][j]];
#pragma unroll
      for (int i = 0; i < 4; i++)
#pragma unroll
        for (int j = 0; j < NJ; j++) acc[i][j] = MFMA16(af[i], bfr[j], acc[i][j]);
    }
  }

  // epilogue: C/D layout col = lane&15, row = quad*4 + reg  [m89-verified]
#pragma unroll
  for (int i = 0; i < 4; i++) {
#pragma unroll
    for (int j = 0; j < NJ; j++) {
#pragma unroll
      for (int r = 0; r < 4; r++) {
        int m = m0 + wm * 64 + i * 16 + quad * 4 + r;
        int n = n0 + wn * 16 * NJ + j * 16 + q16;
        size_t idx = (size_t)m * N + n;
        float v = acc[i][j][r] + bias[n];
        if constexpr (EP == EP_BF16) {
          ((bf16*)outp)[idx] = (bf16)v;
        } else if constexpr (EP == EP_RES_F32) {
          ((float*)outp)[idx] = v + resid[idx];
        } else {
          // gelu(v) = v * sigmoid(1.59577(v + 0.044715 v^3)); exp2 form
          float u = v * (2.3022083f + 0.1029443f * v * v);
          float e = __builtin_amdgcn_exp2f(-u);
          float gv = v * __builtin_amdgcn_rcpf(1.0f + e);
          ((bf16*)outp)[idx] = (bf16)gv;
        }
      }
    }
  }
}

// ---------------------------------------------------------------------------
// Flash attention, bf16 MFMA. qkv: [B,N,3,12,64] bf16 -> out [B,N,768] bf16.
// grid dim3(8,96), b = blockIdx.x -> flat%8 = b: attn batch b runs on XCD b,
// the XCD whose L2 holds batch b's qkv rows dirty and whose L2 proj reads.
// KVBLK=64, 4-wave blocks, in-reg P via swapped QK^T, dbuf K/V LDS, single
// barrier per tile, no-max softmax. V staged reg->4x4 transpose->b64 writes.
// ---------------------------------------------------------------------------
__global__ __launch_bounds__(256, 3) void attn_kernel(const bf16* __restrict__ qkv,
                                                      bf16* __restrict__ o) {
  __shared__ alignas(16) bf16 Kl[2][64 * 64];  // [buf][key][d] swizzled, 16KB
  __shared__ alignas(16) bf16 Vt[2][64 * 72];  // [buf][d][key] swizzled, 18KB
  int tid = threadIdx.x;
  int lane = tid & 63, w = tid >> 6;  // w in 0..3
  int q16 = lane & 15, quad = lane >> 4;
  int b = blockIdx.x;                      // XCD = b
  int h = blockIdx.y % 12;
  int qbase = (blockIdx.y / 12) * 128 + w * 32;
  const int KS = 64 * 2304;

  // Q fragments (B-operand layout n=q16, k=quad*8+j), 2 q-tiles x 2 d-chunks
  bf16x8 qf[2][2];
#pragma unroll
  for (int qt = 0; qt < 2; qt++)
#pragma unroll
    for (int c = 0; c < 2; c++)
      qf[qt][c] = *(const bf16x8*)(qkv +
          (size_t)(b * 1024 + qbase + qt * 16 + q16) * 2304 + h * 64 +
          c * 32 + quad * 8);

  // K DMA: wave w stages keys w*16..w*16+15 (two 8-key chunks); lane fetches
  // the 16B chunk that lands (lane-contiguous DMA) at swizzled granule
  // key*8 + (c ^ (key&7))
  int krow = lane >> 3;
  int kchunk = (lane & 7) ^ krow;
  const bf16* kg0 = qkv + (size_t)(b * 1024 + w * 16 + krow) * 2304 + 768 +
                    h * 64 + kchunk * 8;
  const bf16* kg1 = kg0 + 8 * 2304;
  bf16* kdA[2] = {&Kl[0][w * 1024], &Kl[1][w * 1024]};

  // V staging: thread (kg = tid>>4, dg = tid&15): global b64 loads of
  // V[4kg+i][4dg..4dg+3], in-reg 4x4 transpose, 4x ds_write_b64 into the
  // swizzled V^T: elem (d,key) at granule (d*9 + (key>>3)) ^ ((d>>3)&7),
  // sub-elem key&7. Keys 4kg..4kg+3 are granule-half-aligned -> one b64.
  int kg = tid >> 4;
  int dg = tid & 15;
  const bf16* vgp = qkv + (size_t)(b * 1024 + 4 * kg) * 2304 + 1536 + h * 64 +
                    4 * dg;
  int vw[4];
#pragma unroll
  for (int j = 0; j < 4; j++) {
    int d = 4 * dg + j;
    vw[j] = (((d * 9 + (kg >> 1)) ^ ((d >> 3) & 7)) * 8) + (kg & 1) * 4;
  }
  uint2 vr[4];

  // loop-invariant LDS read offsets
  int koff[4][2];
#pragma unroll
  for (int nc = 0; nc < 4; nc++)
#pragma unroll
    for (int ck = 0; ck < 2; ck++) {
      int key = nc * 16 + q16;
      koff[nc][ck] = (key * 8 + ((ck * 4 + quad) ^ (key & 7))) * 8;
    }
  int voff[2][4];
#pragma unroll
  for (int c = 0; c < 2; c++)
#pragma unroll
    for (int dc = 0; dc < 4; dc++) {
      int d = dc * 16 + q16;
      voff[c][dc] = ((d * 9 + (c * 4 + quad)) ^ ((d >> 3) & 7)) * 8;
    }

  int srcLo = q16 + ((quad & 1) << 5);
  int srcHi = srcLo + 16;
  bool loH = quad < 2;

  float lsum[2] = {0.f, 0.f};
  floatx4 oacc[2][4];
#pragma unroll
  for (int qt = 0; qt < 2; qt++)
#pragma unroll
    for (int dc = 0; dc < 4; dc++) oacc[qt][dc] = (floatx4){0.f, 0.f, 0.f, 0.f};

#define VLOAD()                                                        \
  do {                                                                 \
    _Pragma("unroll") for (int i = 0; i < 4; i++)                      \
        vr[i] = *(const uint2*)(vgp + i * 2304);                       \
    vgp += KS;                                                         \
  } while (0)

#define VWRITE(buf)                                                    \
  do {                                                                 \
    uint lo0 = vr[0].x, lo1 = vr[1].x, lo2 = vr[2].x, lo3 = vr[3].x;   \
    uint hi0 = vr[0].y, hi1 = vr[1].y, hi2 = vr[2].y, hi3 = vr[3].y;   \
    uint2 c0, c1, c2, c3;                                              \
    c0.x = (lo0 & 0xFFFFu) | (lo1 << 16);                              \
    c0.y = (lo2 & 0xFFFFu) | (lo3 << 16);                              \
    c1.x = (lo0 >> 16) | (lo1 & 0xFFFF0000u);                          \
    c1.y = (lo2 >> 16) | (lo3 & 0xFFFF0000u);                          \
    c2.x = (hi0 & 0xFFFFu) | (hi1 << 16);                              \
    c2.y = (hi2 & 0xFFFFu) | (hi3 << 16);                              \
    c3.x = (hi0 >> 16) | (hi1 & 0xFFFF0000u);                          \
    c3.y = (hi2 >> 16) | (hi3 & 0xFFFF0000u);                          \
    *(uint2*)&Vt[buf][vw[0]] = c0;                                     \
    *(uint2*)&Vt[buf][vw[1]] = c1;                                     \
    *(uint2*)&Vt[buf][vw[2]] = c2;                                     \
    *(uint2*)&Vt[buf][vw[3]] = c3;                                     \
  } while (0)

  // prologue: stage tile 0 (K-DMA + V write), prefetch V of tile 1 into regs
  GLDS16(kg0, kdA[0]);
  GLDS16(kg1, kdA[0] + 512);
  kg0 += KS; kg1 += KS;
  VLOAD();
  VWRITE(0);
  VLOAD();

  for (int kt = 0; kt < 16; kt++) {
    int cur = kt & 1, nxt = cur ^ 1;
    __syncthreads();  // buf[cur] staged & visible; buf[nxt] free for reuse
    if (kt < 15) {
      GLDS16(kg0, kdA[nxt]);  // in flight during compute below
      GLDS16(kg1, kdA[nxt] + 512);
      kg0 += KS; kg1 += KS;
      VWRITE(nxt);
      if (kt < 14) VLOAD();  // prefetch V of tile kt+2
    }

    // QK^T (swapped): z[qt][nc][r] = S[key = nc*16 + quad*4 + r][q]
    floatx4 z[2][4];
#pragma unroll
    for (int nc = 0; nc < 4; nc++) {
      bf16x8 k0 = *(const bf16x8*)&Kl[cur][koff[nc][0]];
      bf16x8 k1 = *(const bf16x8*)&Kl[cur][koff[nc][1]];
#pragma unroll
      for (int qt = 0; qt < 2; qt++) {
        floatx4 t = (floatx4){0.f, 0.f, 0.f, 0.f};
        t = MFMA16(k0, qf[qt][0], t);
        t = MFMA16(k1, qf[qt][1], t);
        z[qt][nc] = t;
      }
    }

    bf16x8 vf[2][4];
#pragma unroll
    for (int c = 0; c < 2; c++)
#pragma unroll
      for (int dc = 0; dc < 4; dc++)
        vf[c][dc] = *(const bf16x8*)&Vt[cur][voff[c][dc]];

#pragma unroll
    for (int qt = 0; qt < 2; qt++) {
      float e_[4][4];
#pragma unroll
      for (int nc = 0; nc < 4; nc++)
#pragma unroll
        for (int r = 0; r < 4; r++) {
          e_[nc][r] = __builtin_amdgcn_exp2f(z[qt][nc][r] * 0.18033688011f);
          lsum[qt] += e_[nc][r];
        }
      int P[4][2];
#pragma unroll
      for (int nc = 0; nc < 4; nc++) {
        P[nc][0] = pack2(e_[nc][0], e_[nc][1]);
        P[nc][1] = pack2(e_[nc][2], e_[nc][3]);
      }
      union { int i[4]; bf16x8 v; } pu[2];
#pragma unroll
      for (int c = 0; c < 2; c++) {
        int a0 = __shfl(P[2 * c][0], srcLo, 64), b0 = __shfl(P[2 * c + 1][0], srcLo, 64);
        int a1 = __shfl(P[2 * c][1], srcLo, 64), b1 = __shfl(P[2 * c + 1][1], srcLo, 64);
        int a2 = __shfl(P[2 * c][0], srcHi, 64), b2 = __shfl(P[2 * c + 1][0], srcHi, 64);
        int a3 = __shfl(P[2 * c][1], srcHi, 64), b3 = __shfl(P[2 * c + 1][1], srcHi, 64);
        pu[c].i[0] = loH ? a0 : b0;
        pu[c].i[1] = loH ? a1 : b1;
        pu[c].i[2] = loH ? a2 : b2;
        pu[c].i[3] = loH ? a3 : b3;
      }
#pragma unroll
      for (int dc = 0; dc < 4; dc++) {
        oacc[qt][dc] = MFMA16(pu[0].v, vf[0][dc], oacc[qt][dc]);
        oacc[qt][dc] = MFMA16(pu[1].v, vf[1][dc], oacc[qt][dc]);
      }
    }
  }

  // final: l(q16) = sum over the 4 quads (disjoint key sets), broadcast to
  // output rows q = quad*4 + r via shfl, divide, store
#pragma unroll
  for (int qt = 0; qt < 2; qt++) {
    float s = lsum[qt];
    s += __shfl_xor(s, 16, 64);
    s += __shfl_xor(s, 32, 64);
    float inv = 1.0f / s;
    bf16* op = o + (size_t)(b * 1024 + qbase + qt * 16) * 768 + h * 64;
#pragma unroll
    for (int r = 0; r < 4; r++) {
      float invr = __shfl(inv, quad * 4 + r, 64);
#pragma unroll
      for (int dc = 0; dc < 4; dc++)
        op[(size_t)(quad * 4 + r) * 768 + dc * 16 + q16] =
            (bf16)(oacc[qt][dc][r] * invr);
    }
  }
#undef VLOAD
#undef VWRITE
}

// ---------------------------------------------------------------------------
extern "C" void kernel_launch(void* const* d_in, const int* in_sizes, int n_in,
                              void* d_out, int out_size, void* d_ws, size_t ws_size,
                              hipStream_t stream) {
  (void)in_sizes; (void)n_in; (void)out_size; (void)ws_size;
  const float* x      = (const float*)d_in[0];
  const float* ln1_w  = (const float*)d_in[1];
  const float* ln1_b  = (const float*)d_in[2];
  const float* qkv_w  = (const float*)d_in[3];
  const float* qkv_b  = (const float*)d_in[4];
  const float* proj_w = (const float*)d_in[5];
  const float* proj_b = (const float*)d_in[6];
  const float* ln2_w  = (const float*)d_in[7];
  const float* ln2_b  = (const float*)d_in[8];
  const float* fc1_w  = (const float*)d_in[9];
  const float* fc1_b  = (const float*)d_in[10];
  const float* fc2_w  = (const float*)d_in[11];
  const float* fc2_b  = (const float*)d_in[12];

  char* ws = (char*)d_ws;
  size_t off = 0;
  auto alloc = [&](size_t bytes) {
    void* p = ws + off;
    off += (bytes + 255) & ~(size_t)255;
    return p;
  };
  bf16* wq  = (bf16*)alloc((size_t)2304 * 768 * 2);
  bf16* wp  = (bf16*)alloc((size_t)768 * 768 * 2);
  bf16* wf1 = (bf16*)alloc((size_t)3072 * 768 * 2);
  bf16* wf2 = (bf16*)alloc((size_t)768 * 3072 * 2);
  bf16* slotA = (bf16*)alloc((size_t)8192 * 768 * 2);   // h1 / ob / h2
  bf16* slotB = (bf16*)alloc((size_t)8192 * 3072 * 2);  // qkv / fc1-out
  float* x1 = (float*)alloc((size_t)8192 * 768 * 4);

  bf16* h1 = slotA;
  bf16* qkvb = slotB;
  bf16* ob = slotA;
  bf16* h2 = slotA;
  bf16* hm = slotB;

  pre_kernel<<<dim3(8, 1024 + 864), 256, 0, stream>>>(
      x, ln1_w, ln1_b, h1,
      qkv_w, wq, 2304 * 768 / 4, proj_w, wp, 768 * 768 / 4,
      fc1_w, wf1, 3072 * 768 / 4, fc2_w, wf2, 768 * 3072 / 4);

  gemm_bt<EP_BF16, 6, 64><<<dim3(12, 64), 256, 0, stream>>>(
      h1, wq, qkv_b, nullptr, qkvb, 8192, 2304, 768);
  attn_kernel<<<dim3(8, 96), 256, 0, stream>>>(qkvb, ob);
  gemm_bt<EP_RES_F32, 2, 128><<<dim3(12, 64), 256, 0, stream>>>(
      ob, wp, proj_b, x, x1, 8192, 768, 768);
  ln_kernel<<<dim3(8, 1024), 256, 0, stream>>>(x1, ln2_w, ln2_b, h2);
  gemm_bt<EP_GELU_BF16, 6, 64><<<dim3(16, 64), 256, 0, stream>>>(
      h2, wf1, fc1_b, nullptr, hm, 8192, 3072, 768);
  gemm_bt<EP_RES_F32, 2, 128><<<dim3(12, 64), 256, 0, stream>>>(
      hm, wf2, fc2_b, x1, (float*)d_out, 8192, 768, 3072);
}